// Round 6
// baseline (211.205 us; speedup 1.0000x reference)
//
#include <hip/hip_runtime.h>
#include <stdint.h>

typedef __attribute__((ext_vector_type(8)))  short  short8;
typedef __attribute__((ext_vector_type(8)))  __bf16 bf16x8;
typedef __attribute__((ext_vector_type(16))) float  floatx16;
typedef __attribute__((ext_vector_type(4)))  float  floatx4;
typedef __attribute__((ext_vector_type(2)))  float  float2v;
typedef __attribute__((ext_vector_type(4)))  uint32_t uint4v;

union Frag { short8 s; bf16x8 v; uint4v d; };
union FU   { float f; uint32_t u; };

// round-to-nearest-even f32 -> bf16 (setup only)
__device__ __forceinline__ short f2bf(float f) {
    FU x; x.f = f;
    uint32_t r = x.u + 0x7fffu + ((x.u >> 16) & 1u);
    return (short)(r >> 16);
}

// pack two f32 -> bf16x2 dword, round-half-up: 2 adds + 1 v_perm
__device__ __forceinline__ uint32_t pack_bf2(float lo, float hi) {
    FU a, b; a.f = lo; b.f = hi;
    return __builtin_amdgcn_perm(b.u + 0x8000u, a.u + 0x8000u, 0x07060302u);
}

__device__ __forceinline__ float fexp2(float x) { return __builtin_amdgcn_exp2f(x); }
__device__ __forceinline__ float frcp(float x)  { return __builtin_amdgcn_rcpf(x); }
__device__ __forceinline__ float fclamp(float x, float lo, float hi) {
#if __has_builtin(__builtin_amdgcn_fmed3f)
    return __builtin_amdgcn_fmed3f(x, lo, hi);
#else
    return fminf(fmaxf(x, lo), hi);
#endif
}

// T = exp2(clamp(arg)) + 1 for the (acc0[r], acc1[r]) pair (pk_add for +1)
__device__ __forceinline__ float2v tpair(float a, float b) {
    float2v t;
    t.x = fexp2(fclamp(a, -30.0f, 30.0f));
    t.y = fexp2(fclamp(b, -30.0f, 30.0f));
    return t + 1.0f;
}

// y[b] = a0 + sum_k bk[k] * tanh(ck[k,:].z[b,:] + dk[k])
//
// D = mfma_32x32x16_bf16(A=s*ck, B=z, C=s*dk) -> D[node][row] = s*(dot+dk),
// s = 2*log2(e); col(lane&31)=batch row, row(reg-map)=node.
// tanh(t) = 1 - 2/(exp2(s*t)+1); 4-way shared denominator:
//   b0/t0+..+b3/t3 = [(b0t1+b1t0)t2t3 + (b2t3+b3t2)t0t1] * rcp(t0t1t2t3)
// exp2 arg clamped +-30 => 4-product <= 2^121, no overflow; clamp err ~2e-9.
//
// R6: cold-pass memory fix. R1-R5 single-pass kernels were all stuck at
// ~75us vs a 33us warm-pass floor (R4 nrep=4 data): conditional prefetch
// loads force conservative s_waitcnt vmcnt(0) at loop merges -> full ~900cy
// HBM latency exposed per refill. Now: depth-4 ring buffer, UNCONDITIONAL
// refills with a clamped (s_min, branch-free) tile index -- every iteration
// issues exactly 2 dwordx4 loads, so the waitcnt insertion can use precise
// vmcnt(N) and keep 8 loads in flight across iterations. Tail iterations
// redundantly re-read the last tile (L1 hit, harmless).
__global__ __launch_bounds__(256) void mave_kernel(
    const float* __restrict__ z,
    const float* __restrict__ a0,
    const float* __restrict__ bk,
    const float* __restrict__ ck,
    const float* __restrict__ dk,
    float* __restrict__ out,
    int ntiles)
{
    const int lane = threadIdx.x & 63;
    const int m    = lane & 31;
    const int g    = lane >> 5;
    const float S  = 2.885390081777927f;  // 2*log2(e)

    // A-operand fragments: rows of s*ck (node = m and m+32), k = g*8+e
    Frag af0, af1;
    {
        const float* c0 = ck + m * 16 + g * 8;
        const float* c1 = c0 + 32 * 16;
        #pragma unroll
        for (int e = 0; e < 8; ++e) {
            af0.s[e] = f2bf(c0[e] * S);
            af1.s[e] = f2bf(c1[e] * S);
        }
    }

    // C-init = s*dk[node]; node map (reg&3)+8*(reg>>2)+4*g.
    // nbp = -2*bk packed bf16x2 (16 VGPRs, unpacked at use: 2 ops/node-pair)
    floatx16 cinit0, cinit1;
    uint32_t nbp[16];
    #pragma unroll
    for (int r = 0; r < 16; ++r) {
        int n = (r & 3) + 8 * (r >> 2) + 4 * g;
        cinit0[r] = S * dk[n];
        cinit1[r] = S * dk[n + 32];
        nbp[r] = pack_bf2(-2.0f * bk[n], -2.0f * bk[n + 32]);
    }

    float base = a0[0];
    for (int k = 0; k < 64; ++k) base += bk[k];

    const int wid = (int)((blockIdx.x * blockDim.x + threadIdx.x) >> 6);
    const int nw  = (int)((gridDim.x * blockDim.x) >> 6);
    const int per  = (ntiles + nw - 1) / nw;       // tiles per wave (8)
    const int tbeg = wid * per;
    const int tend = (tbeg + per < ntiles) ? tbeg + per : ntiles;
    if (tbeg >= tend) return;
    const int tlast = tend - 1;

    // depth-4 ring of tile buffers (2 x dwordx4 each); lane base pointer
    const float* zb = z + (size_t)m * 16 + g * 8;  // + tile*512 floats
    floatx4 ring[4][2];
    #pragma unroll
    for (int i = 0; i < 4; ++i) {
        int ti = tbeg + i; if (ti > tlast) ti = tlast;   // s_min, no branch
        const float* zp = zb + (size_t)ti * 512;
        ring[i][0] = *(const floatx4*)zp;
        ring[i][1] = *(const floatx4*)(zp + 4);
    }

    #pragma unroll 4
    for (int t = tbeg; t < tend; ++t) {
        const int slot = (t - tbeg) & 3;

        // consume slot -> bf16 B-frag
        Frag bfr;
        bfr.d[0] = pack_bf2(ring[slot][0].x, ring[slot][0].y);
        bfr.d[1] = pack_bf2(ring[slot][0].z, ring[slot][0].w);
        bfr.d[2] = pack_bf2(ring[slot][1].x, ring[slot][1].y);
        bfr.d[3] = pack_bf2(ring[slot][1].z, ring[slot][1].w);

        // unconditional refill, clamped index (tail re-reads last tile)
        int tf = t + 4; if (tf > tlast) tf = tlast;
        {
            const float* zp = zb + (size_t)tf * 512;
            ring[slot][0] = *(const floatx4*)zp;
            ring[slot][1] = *(const floatx4*)(zp + 4);
        }

        floatx16 acc0 = __builtin_amdgcn_mfma_f32_32x32x16_bf16(af0.v, bfr.v, cinit0, 0, 0, 0);
        floatx16 acc1 = __builtin_amdgcn_mfma_f32_32x32x16_bf16(af1.v, bfr.v, cinit1, 0, 0, 0);

        float2v Ya = {0.0f, 0.0f}, Yb = {0.0f, 0.0f};
        #pragma unroll
        for (int r = 0; r < 16; r += 4) {
            float2v T0 = tpair(acc0[r+0], acc1[r+0]);
            float2v T1 = tpair(acc0[r+1], acc1[r+1]);
            float2v T2 = tpair(acc0[r+2], acc1[r+2]);
            float2v T3 = tpair(acc0[r+3], acc1[r+3]);
            float2v P01 = T0 * T1, P23 = T2 * T3, P = P01 * P23;
            float2v R; R.x = frcp(P.x); R.y = frcp(P.y);
            FU l0, h0, l1, h1, l2, h2, l3, h3;
            l0.u = nbp[r+0] << 16; h0.u = nbp[r+0] & 0xffff0000u;
            l1.u = nbp[r+1] << 16; h1.u = nbp[r+1] & 0xffff0000u;
            l2.u = nbp[r+2] << 16; h2.u = nbp[r+2] & 0xffff0000u;
            l3.u = nbp[r+3] << 16; h3.u = nbp[r+3] & 0xffff0000u;
            float2v nb0 = {l0.f, h0.f}, nb1 = {l1.f, h1.f};
            float2v nb2 = {l2.f, h2.f}, nb3 = {l3.f, h3.f};
            float2v n01 = nb0 * T1 + nb1 * T0;
            float2v n23 = nb2 * T3 + nb3 * T2;
            float2v num = n01 * P23 + n23 * P01;
            if (r & 4) Yb += num * R; else Ya += num * R;
        }
        float2v Yv = Ya + Yb;
        float y = Yv.x + Yv.y;
        y += __shfl_xor(y, 32, 64);
        if (g == 0) out[t * 32 + m] = base + y;
    }
}

extern "C" void kernel_launch(void* const* d_in, const int* in_sizes, int n_in,
                              void* d_out, int out_size, void* d_ws, size_t ws_size,
                              hipStream_t stream) {
    const float* z  = (const float*)d_in[0];
    const float* a0 = (const float*)d_in[1];
    const float* bk = (const float*)d_in[2];
    const float* ck = (const float*)d_in[3];
    const float* dk = (const float*)d_in[4];
    float* out = (float*)d_out;

    const int B      = in_sizes[0] / 16;   // z is [B,16]
    const int ntiles = B / 32;             // 32 batch rows per wave-tile

    dim3 grid(2048), block(256);           // 8192 waves, 8-tile chunk each
    hipLaunchKernelGGL(mave_kernel, grid, block, 0, stream,
                       z, a0, bk, ck, dk, out, ntiles);
}

// Round 7
// 199.677 us; speedup vs baseline: 1.0577x; 1.0577x over previous
//
#include <hip/hip_runtime.h>
#include <stdint.h>

typedef __attribute__((ext_vector_type(8)))  short  short8;
typedef __attribute__((ext_vector_type(8)))  __bf16 bf16x8;
typedef __attribute__((ext_vector_type(16))) float  floatx16;
typedef __attribute__((ext_vector_type(4)))  float  floatx4;
typedef __attribute__((ext_vector_type(2)))  float  float2v;
typedef __attribute__((ext_vector_type(4)))  uint32_t uint4v;

union Frag { short8 s; bf16x8 v; uint4v d; };
union FU   { float f; uint32_t u; };

// round-to-nearest-even f32 -> bf16 (setup only)
__device__ __forceinline__ short f2bf(float f) {
    FU x; x.f = f;
    uint32_t r = x.u + 0x7fffu + ((x.u >> 16) & 1u);
    return (short)(r >> 16);
}

// pack two f32 -> bf16x2 dword, round-half-up: 2 adds + 1 v_perm
__device__ __forceinline__ uint32_t pack_bf2(float lo, float hi) {
    FU a, b; a.f = lo; b.f = hi;
    return __builtin_amdgcn_perm(b.u + 0x8000u, a.u + 0x8000u, 0x07060302u);
}

__device__ __forceinline__ float fexp2(float x) { return __builtin_amdgcn_exp2f(x); }
__device__ __forceinline__ float frcp(float x)  { return __builtin_amdgcn_rcpf(x); }
__device__ __forceinline__ float fclamp(float x, float lo, float hi) {
#if __has_builtin(__builtin_amdgcn_fmed3f)
    return __builtin_amdgcn_fmed3f(x, lo, hi);
#else
    return fminf(fmaxf(x, lo), hi);
#endif
}

// T = exp2(clamp(arg)) + 1 for the (acc0[r], acc1[r]) pair (pk_add for +1)
__device__ __forceinline__ float2v tpair(float a, float b) {
    float2v t;
    t.x = fexp2(fclamp(a, -30.0f, 30.0f));
    t.y = fexp2(fclamp(b, -30.0f, 30.0f));
    return t + 1.0f;
}

// y[b] = a0 + sum_k bk[k] * tanh(ck[k,:].z[b,:] + dk[k])
//
// D = mfma_32x32x16_bf16(A=s*ck, B=z, C=s*dk) -> D[node][row] = s*(dot+dk),
// s = 2*log2(e); col(lane&31)=batch row, row(reg-map)=node.
// tanh(t) = 1 - 2/(exp2(s*t)+1); 4-way shared denominator:
//   b0/t0+..+b3/t3 = [(b0t1+b1t0)t2t3 + (b2t3+b3t2)t0t1] * rcp(t0t1t2t3)
// exp2 arg clamped +-30 => 4-product <= 2^121, no overflow; clamp err ~2e-9.
//
// R7: STRUCTURAL fix for the latency-bound cold pass. R2/R6 in-loop
// pipelining variants all pinned at ~77-83us (1.7 TB/s effective) -- the
// loop back-edge forces conservative waitcnt, same pathology as learn_hip
// m131-m141. Now each wave is STRAIGHT-LINE: exactly 4 tiles, all 8
// dwordx4 loads issued before any consume (no back-edge, no conditional
// loads -> compiler must emit monotone vmcnt(6/4/2/0)). 8 loads/wave in
// flight x 4 waves/SIMD = 32KB outstanding per SIMD >> latency-BW product.
__global__ __launch_bounds__(256) void mave_kernel(
    const float* __restrict__ z,
    const float* __restrict__ a0,
    const float* __restrict__ bk,
    const float* __restrict__ ck,
    const float* __restrict__ dk,
    float* __restrict__ out,
    int ntiles)
{
    const int lane = threadIdx.x & 63;
    const int m    = lane & 31;
    const int g    = lane >> 5;
    const float S  = 2.885390081777927f;  // 2*log2(e)

    const int wid   = (int)((blockIdx.x * blockDim.x + threadIdx.x) >> 6);
    const int tile0 = wid * 4;
    if (tile0 >= ntiles) return;
    const int tlast = ntiles - 1;

    // ---- issue ALL z loads first (8x dwordx4, monotone vmcnt) ----
    floatx4 zb[4][2];
    {
        const float* zp = z + (size_t)m * 16 + g * 8;
        #pragma unroll
        for (int i = 0; i < 4; ++i) {
            int ti = tile0 + i; if (ti > tlast) ti = tlast;  // tail clamp (benign rewrite)
            const float* q = zp + (size_t)ti * 512;
            zb[i][0] = *(const floatx4*)q;
            zb[i][1] = *(const floatx4*)(q + 4);
        }
    }

    // ---- preamble overlaps the z-load latency ----
    // A-operand fragments: rows of s*ck (node = m and m+32), k = g*8+e
    Frag af0, af1;
    {
        const float* c0 = ck + m * 16 + g * 8;
        const float* c1 = c0 + 32 * 16;
        #pragma unroll
        for (int e = 0; e < 8; ++e) {
            af0.s[e] = f2bf(c0[e] * S);
            af1.s[e] = f2bf(c1[e] * S);
        }
    }
    // C-init = s*dk[node]; node map (reg&3)+8*(reg>>2)+4*g.
    // nbp = -2*bk packed bf16x2 (unpacked at use: 2 ops/node-pair)
    floatx16 cinit0, cinit1;
    uint32_t nbp[16];
    #pragma unroll
    for (int r = 0; r < 16; ++r) {
        int n = (r & 3) + 8 * (r >> 2) + 4 * g;
        cinit0[r] = S * dk[n];
        cinit1[r] = S * dk[n + 32];
        nbp[r] = pack_bf2(-2.0f * bk[n], -2.0f * bk[n + 32]);
    }
    float base = a0[0];
    for (int k = 0; k < 64; ++k) base += bk[k];

    // ---- consume in load order ----
    #pragma unroll
    for (int i = 0; i < 4; ++i) {
        Frag bfr;
        bfr.d[0] = pack_bf2(zb[i][0].x, zb[i][0].y);
        bfr.d[1] = pack_bf2(zb[i][0].z, zb[i][0].w);
        bfr.d[2] = pack_bf2(zb[i][1].x, zb[i][1].y);
        bfr.d[3] = pack_bf2(zb[i][1].z, zb[i][1].w);

        floatx16 acc0 = __builtin_amdgcn_mfma_f32_32x32x16_bf16(af0.v, bfr.v, cinit0, 0, 0, 0);
        floatx16 acc1 = __builtin_amdgcn_mfma_f32_32x32x16_bf16(af1.v, bfr.v, cinit1, 0, 0, 0);

        float2v Ya = {0.0f, 0.0f}, Yb = {0.0f, 0.0f};
        #pragma unroll
        for (int r = 0; r < 16; r += 4) {
            float2v T0 = tpair(acc0[r+0], acc1[r+0]);
            float2v T1 = tpair(acc0[r+1], acc1[r+1]);
            float2v T2 = tpair(acc0[r+2], acc1[r+2]);
            float2v T3 = tpair(acc0[r+3], acc1[r+3]);
            float2v P01 = T0 * T1, P23 = T2 * T3, P = P01 * P23;
            float2v R; R.x = frcp(P.x); R.y = frcp(P.y);
            FU l0, h0, l1, h1, l2, h2, l3, h3;
            l0.u = nbp[r+0] << 16; h0.u = nbp[r+0] & 0xffff0000u;
            l1.u = nbp[r+1] << 16; h1.u = nbp[r+1] & 0xffff0000u;
            l2.u = nbp[r+2] << 16; h2.u = nbp[r+2] & 0xffff0000u;
            l3.u = nbp[r+3] << 16; h3.u = nbp[r+3] & 0xffff0000u;
            float2v nb0 = {l0.f, h0.f}, nb1 = {l1.f, h1.f};
            float2v nb2 = {l2.f, h2.f}, nb3 = {l3.f, h3.f};
            float2v n01 = nb0 * T1 + nb1 * T0;
            float2v n23 = nb2 * T3 + nb3 * T2;
            float2v num = n01 * P23 + n23 * P01;
            if (r & 4) Yb += num * R; else Ya += num * R;
        }
        float2v Yv = Ya + Yb;
        float y = Yv.x + Yv.y;
        y += __shfl_xor(y, 32, 64);
        int ti = tile0 + i; if (ti > tlast) ti = tlast;
        if (g == 0) out[ti * 32 + m] = base + y;
    }
}

extern "C" void kernel_launch(void* const* d_in, const int* in_sizes, int n_in,
                              void* d_out, int out_size, void* d_ws, size_t ws_size,
                              hipStream_t stream) {
    const float* z  = (const float*)d_in[0];
    const float* a0 = (const float*)d_in[1];
    const float* bk = (const float*)d_in[2];
    const float* ck = (const float*)d_in[3];
    const float* dk = (const float*)d_in[4];
    float* out = (float*)d_out;

    const int B      = in_sizes[0] / 16;       // z is [B,16]
    const int ntiles = B / 32;                 // 32 batch rows per wave-tile

    // 4 tiles per wave, straight-line; 1 block = 4 waves = 16 tiles
    const int blocks = (ntiles + 15) / 16;     // 4096 at B=2M
    hipLaunchKernelGGL(mave_kernel, dim3(blocks), dim3(256), 0, stream,
                       z, a0, bk, ck, dk, out, ntiles);
}